// Round 11
// baseline (811.907 us; speedup 1.0000x reference)
//
#include <hip/hip_runtime.h>
#include <hip/hip_fp16.h>
#include <hip/hip_cooperative_groups.h>

namespace cg = cooperative_groups;

#define WG 256

typedef _Float16 f16;
typedef _Float16 hv2 __attribute__((ext_vector_type(2)));
typedef _Float16 f16x4 __attribute__((ext_vector_type(4)));
typedef _Float16 f16x8 __attribute__((ext_vector_type(8)));
typedef float f32x4 __attribute__((ext_vector_type(4)));

// ---------------- cooperative CSR build + misc prep, single launch ----------------
// P0: deg=0, W transposes (f16), pairs->float. P1: count+rank. P2: per-tile scan
// (+dinv). P3: tile-sum scan. P4: apply offsets. P5: fill esrc.
__global__ __launch_bounds__(WG, 4) void k_csr(const int* __restrict__ src,
                                               const int* __restrict__ dst,
                                               int* __restrict__ deg,
                                               int* __restrict__ rank,
                                               int* __restrict__ base,
                                               int* __restrict__ bsum,
                                               float* __restrict__ dinv,
                                               const float* __restrict__ Wg,
                                               f16* __restrict__ Wgt,
                                               const float* __restrict__ W1,
                                               f16* __restrict__ W1t,
                                               const int* __restrict__ pairs,
                                               float* __restrict__ outp,
                                               int* __restrict__ esrc,
                                               int n, int e, int nb, int p4) {
    cg::grid_group grid = cg::this_grid();
    __shared__ int t[WG];
    const int tid = threadIdx.x;
    const int G = gridDim.x * WG;
    const int gtid = blockIdx.x * WG + tid;

    // P0: init + independent misc work
    for (int i = gtid; i < n; i += G) deg[i] = 0;
    for (int i = gtid; i < 128 * 128; i += G) {
        int k = i & 127, nI = i >> 7;
        Wgt[i] = (f16)Wg[(size_t)k * 128 + nI];
    }
    for (int i = gtid; i < 128 * 256; i += G) {
        int k = i & 255, nI = i >> 8;
        W1t[i] = (f16)W1[(size_t)k * 128 + nI];
    }
    for (int i = gtid; i < p4; i += G) {
        int4 v = ((const int4*)pairs)[i];
        ((float4*)outp)[i] = make_float4((float)v.x, (float)v.y, (float)v.z, (float)v.w);
    }
    grid.sync();

    // P1: in-degree count + per-edge rank
    for (int i = gtid; i < e; i += G) rank[i] = atomicAdd(&deg[dst[i]], 1);
    grid.sync();

    // P2: per-tile exclusive scan of deg into base; tile totals to bsum; dinv
    for (int tile = blockIdx.x; tile < nb; tile += gridDim.x) {
        int i = tile * WG + tid;
        int v = (i < n) ? deg[i] : 0;
        if (i < n) dinv[i] = rsqrtf((float)(v + 1));
        t[tid] = v;
        __syncthreads();
        for (int o = 1; o < WG; o <<= 1) {
            int add = (tid >= o) ? t[tid - o] : 0;
            __syncthreads();
            t[tid] += add;
            __syncthreads();
        }
        if (i < n) base[i] = t[tid] - v;
        if (tid == WG - 1) bsum[tile] = t[WG - 1];
        __syncthreads();
    }
    grid.sync();

    // P3: exclusive scan of tile totals (nb <= 256) by block 0
    if (blockIdx.x == 0) {
        int v = (tid < nb) ? bsum[tid] : 0;
        t[tid] = v;
        __syncthreads();
        for (int o = 1; o < WG; o <<= 1) {
            int add = (tid >= o) ? t[tid - o] : 0;
            __syncthreads();
            t[tid] += add;
            __syncthreads();
        }
        if (tid < nb) bsum[tid] = t[tid] - v;
    }
    grid.sync();

    // P4: apply tile offsets
    for (int i = gtid; i < n; i += G) base[i] += bsum[i >> 8];
    if (gtid == 0) base[n] = e;
    grid.sync();

    // P5: fill CSR (no atomics — slot = base[dst] + rank)
    for (int i = gtid; i < e; i += G) esrc[base[dst[i]] + rank[i]] = src[i];
}

// ---------- MFMA GEMM: Hpk'[r][c] = half2 of (A@W)[r][{c,c+64}] * dinv[r]
__global__ __launch_bounds__(WG) void k_mm_hpk(const float* __restrict__ A,
                                               const f16* __restrict__ Wt,  // [128][128]
                                               const float* __restrict__ dinv,
                                               __half2* __restrict__ Out, int n) {
    __shared__ f16 As[64][136];
    __shared__ f16 Bs[128][136];
    const int tid = threadIdx.x;
    const int row0 = blockIdx.x * 64;
    for (int f = tid; f < 128 * 16; f += WG) {
        int r = f >> 4, c = f & 15;
        *(float4*)&Bs[r][c * 8] = ((const float4*)Wt)[r * 16 + c];
    }
    for (int f = tid; f < 64 * 32; f += WG) {
        int r = f >> 5, c = f & 31;
        float4 v = make_float4(0.f, 0.f, 0.f, 0.f);
        if (row0 + r < n) v = ((const float4*)A)[(size_t)(row0 + r) * 32 + c];
        *(f16x4*)&As[r][c * 4] = (f16x4){(f16)v.x, (f16)v.y, (f16)v.z, (f16)v.w};
    }
    __syncthreads();
    const int wv = tid >> 6, lane = tid & 63, m = lane & 15, quad = lane >> 4;
    f32x4 acc[8];
#pragma unroll
    for (int t = 0; t < 8; ++t) acc[t] = (f32x4){0.f, 0.f, 0.f, 0.f};
#pragma unroll
    for (int kk = 0; kk < 4; ++kk) {
        f16x8 af = *(f16x8*)&As[wv * 16 + m][kk * 32 + quad * 8];
#pragma unroll
        for (int t = 0; t < 8; ++t) {
            f16x8 bf = *(f16x8*)&Bs[t * 16 + m][kk * 32 + quad * 8];
            acc[t] = __builtin_amdgcn_mfma_f32_16x16x32_f16(af, bf, acc[t], 0, 0, 0);
        }
    }
#pragma unroll
    for (int r = 0; r < 4; ++r) {
        int row = row0 + wv * 16 + quad * 4 + r;
        if (row < n) {
            float dv = dinv[row];
#pragma unroll
            for (int t = 0; t < 4; ++t)
                Out[(size_t)row * 64 + t * 16 + m] =
                    __floats2half2_rn(acc[t][r] * dv, acc[t + 4][r] * dv);
        }
    }
}

// ---------- fused gather + U/V MFMA GEMM.
// Phase A: gather 64 nodes (16 lanes/node, 4 passes): out_h fp32 to global,
// f16 into As (MFMA A-tile). Phase B: U = h@W1a + b1, V = h@W1b, packed (c,c+64).
__global__ __launch_bounds__(WG) void k_gather_uv(const __half2* __restrict__ Hpk,
                                                  const float* __restrict__ dinv,
                                                  const float* __restrict__ bg,
                                                  const int* __restrict__ base,
                                                  const int* __restrict__ esrc,
                                                  const f16* __restrict__ W1t,
                                                  const float* __restrict__ b1,
                                                  float* __restrict__ outh,
                                                  __half2* __restrict__ Up,
                                                  __half2* __restrict__ Vp, int n) {
    __shared__ f16 As[64][136];
    __shared__ f16 Bs[128][136];
    const int tid = threadIdx.x;
    const int row0 = blockIdx.x * 64;
    const int sub = tid & 15;

#pragma unroll
    for (int pass = 0; pass < 4; ++pass) {
        int r = pass * 16 + (tid >> 4);
        int node = row0 + r;
        if (node < n) {
            int4 hh = *(const int4*)(Hpk + (size_t)node * 64 + 4 * sub);
            const int* hp = (const int*)&hh;
            float accl[4], acch[4];
#pragma unroll
            for (int k = 0; k < 4; ++k) {
                hv2 h = __builtin_bit_cast(hv2, hp[k]);
                accl[k] = (float)h[0];
                acch[k] = (float)h[1];
            }
            int j = base[node], jend = base[node + 1];
            for (; j + 4 <= jend; j += 4) {
                int s0 = esrc[j], s1 = esrc[j + 1], s2i = esrc[j + 2], s3 = esrc[j + 3];
                int4 r0 = *(const int4*)(Hpk + (size_t)s0 * 64 + 4 * sub);
                int4 r1 = *(const int4*)(Hpk + (size_t)s1 * 64 + 4 * sub);
                int4 r2 = *(const int4*)(Hpk + (size_t)s2i * 64 + 4 * sub);
                int4 r3 = *(const int4*)(Hpk + (size_t)s3 * 64 + 4 * sub);
                const int* p0 = (const int*)&r0;
                const int* p1 = (const int*)&r1;
                const int* p2 = (const int*)&r2;
                const int* p3 = (const int*)&r3;
#pragma unroll
                for (int k = 0; k < 4; ++k) {
                    hv2 h0 = __builtin_bit_cast(hv2, p0[k]);
                    hv2 h1 = __builtin_bit_cast(hv2, p1[k]);
                    hv2 h2 = __builtin_bit_cast(hv2, p2[k]);
                    hv2 h3 = __builtin_bit_cast(hv2, p3[k]);
                    accl[k] += (float)h0[0] + (float)h1[0] + (float)h2[0] + (float)h3[0];
                    acch[k] += (float)h0[1] + (float)h1[1] + (float)h2[1] + (float)h3[1];
                }
            }
            for (; j < jend; ++j) {
                int s = esrc[j];
                int4 rr = *(const int4*)(Hpk + (size_t)s * 64 + 4 * sub);
                const int* pr = (const int*)&rr;
#pragma unroll
                for (int k = 0; k < 4; ++k) {
                    hv2 h = __builtin_bit_cast(hv2, pr[k]);
                    accl[k] += (float)h[0];
                    acch[k] += (float)h[1];
                }
            }
            float dv = dinv[node];
            float4 blo = *(const float4*)(bg + 4 * sub);
            float4 bhi = *(const float4*)(bg + 4 * sub + 64);
            float ol[4], oh[4];
#pragma unroll
            for (int k = 0; k < 4; ++k) {
                ol[k] = fmaf(accl[k], dv, ((const float*)&blo)[k]);
                oh[k] = fmaf(acch[k], dv, ((const float*)&bhi)[k]);
            }
            *(float4*)&outh[(size_t)node * 128 + 4 * sub] =
                make_float4(ol[0], ol[1], ol[2], ol[3]);
            *(float4*)&outh[(size_t)node * 128 + 64 + 4 * sub] =
                make_float4(oh[0], oh[1], oh[2], oh[3]);
            *(f16x4*)&As[r][4 * sub] = (f16x4){(f16)ol[0], (f16)ol[1], (f16)ol[2], (f16)ol[3]};
            *(f16x4*)&As[r][64 + 4 * sub] = (f16x4){(f16)oh[0], (f16)oh[1], (f16)oh[2], (f16)oh[3]};
        }
        // rows >= n left uninit in As: MFMA row m only feeds C row m (store-guarded)
    }

    const int wv = tid >> 6, lane = tid & 63, m = lane & 15, quad = lane >> 4;
    f32x4 acc[8];
#pragma unroll
    for (int ph = 0; ph < 2; ++ph) {
        __syncthreads();  // As complete (ph0) / prior Bs consumed (ph1)
        for (int f = tid; f < 128 * 16; f += WG) {
            int r = f >> 4, c = f & 15;
            *(float4*)&Bs[r][c * 8] = *(const float4*)(W1t + (size_t)r * 256 + ph * 128 + c * 8);
        }
        __syncthreads();
#pragma unroll
        for (int t = 0; t < 8; ++t) acc[t] = (f32x4){0.f, 0.f, 0.f, 0.f};
#pragma unroll
        for (int kk = 0; kk < 4; ++kk) {
            f16x8 af = *(f16x8*)&As[wv * 16 + m][kk * 32 + quad * 8];
#pragma unroll
            for (int t = 0; t < 8; ++t) {
                f16x8 bf = *(f16x8*)&Bs[t * 16 + m][kk * 32 + quad * 8];
                acc[t] = __builtin_amdgcn_mfma_f32_16x16x32_f16(af, bf, acc[t], 0, 0, 0);
            }
        }
        __half2* Out = ph ? Vp : Up;
#pragma unroll
        for (int t = 0; t < 4; ++t) {
            float bl = 0.f, bh = 0.f;
            if (!ph) { bl = b1[t * 16 + m]; bh = b1[t * 16 + m + 64]; }
#pragma unroll
            for (int r = 0; r < 4; ++r) {
                int row = row0 + wv * 16 + quad * 4 + r;
                if (row < n)
                    Out[(size_t)row * 64 + t * 16 + m] =
                        __floats2half2_rn(acc[t][r] + bl, acc[t + 4][r] + bh);
            }
        }
    }
}

// --------- 2 pairs per 16-lane group (8/wave): logit = relu(U[a]+V[b]).W2 + b2
__global__ __launch_bounds__(WG) void k_pair8(const __half2* __restrict__ U,
                                              const __half2* __restrict__ V,
                                              const float* __restrict__ W2,
                                              const float* __restrict__ b2,
                                              const int* __restrict__ pairs,
                                              float* __restrict__ out_logit, int p) {
    int wv = (blockIdx.x * WG + threadIdx.x) >> 6;
    int lane = threadIdx.x & 63;
    int g = lane >> 4, sub = lane & 15;
    int q0 = wv * 8 + g, q1 = q0 + 4;
    bool v0 = (q0 < p), v1 = (q1 < p);
    if (!v0) return;
    int qa0 = q0, qa1 = v1 ? q1 : q0;
    int a0 = pairs[2 * qa0], b0 = pairs[2 * qa0 + 1];
    int a1 = pairs[2 * qa1], b1i = pairs[2 * qa1 + 1];

    float4 w2lo = ((const float4*)W2)[sub];
    float4 w2hi = ((const float4*)(W2 + 64))[sub];
    hv2 w2h[4];
    w2h[0] = hv2{(f16)w2lo.x, (f16)w2hi.x};
    w2h[1] = hv2{(f16)w2lo.y, (f16)w2hi.y};
    w2h[2] = hv2{(f16)w2lo.z, (f16)w2hi.z};
    w2h[3] = hv2{(f16)w2lo.w, (f16)w2hi.w};

    int4 u0 = *(const int4*)(U + (size_t)a0 * 64 + 4 * sub);
    int4 vv0 = *(const int4*)(V + (size_t)b0 * 64 + 4 * sub);
    int4 u1 = *(const int4*)(U + (size_t)a1 * 64 + 4 * sub);
    int4 vv1 = *(const int4*)(V + (size_t)b1i * 64 + 4 * sub);
    const int* ui0 = (const int*)&u0;
    const int* vi0 = (const int*)&vv0;
    const int* ui1 = (const int*)&u1;
    const int* vi1 = (const int*)&vv1;

    const hv2 z2 = hv2{(f16)0.f, (f16)0.f};
    float p0 = 0.f, p1 = 0.f;
#pragma unroll
    for (int k = 0; k < 4; ++k) {
        hv2 s0 = __builtin_bit_cast(hv2, ui0[k]) + __builtin_bit_cast(hv2, vi0[k]);
        hv2 s1 = __builtin_bit_cast(hv2, ui1[k]) + __builtin_bit_cast(hv2, vi1[k]);
        p0 = __builtin_amdgcn_fdot2(__builtin_elementwise_max(s0, z2), w2h[k], p0, false);
        p1 = __builtin_amdgcn_fdot2(__builtin_elementwise_max(s1, z2), w2h[k], p1, false);
    }
#pragma unroll
    for (int m = 1; m < 16; m <<= 1) {
        p0 += __shfl_xor(p0, m, 64);
        p1 += __shfl_xor(p1, m, 64);
    }
    if (sub == 0) {
        float bb = b2[0];
        out_logit[q0] = p0 + bb;
        if (v1) out_logit[q1] = p1 + bb;
    }
}

extern "C" void kernel_launch(void* const* d_in, const int* in_sizes, int n_in,
                              void* d_out, int out_size, void* d_ws, size_t ws_size,
                              hipStream_t stream) {
    const float* x     = (const float*)d_in[0];
    const int*   eidx  = (const int*)d_in[1];
    const int*   pairs = (const int*)d_in[2];
    const float* W_gcn = (const float*)d_in[3];
    const float* b_gcn = (const float*)d_in[4];
    const float* W1    = (const float*)d_in[5];
    const float* b1    = (const float*)d_in[6];
    const float* W2    = (const float*)d_in[7];
    const float* b2    = (const float*)d_in[8];

    const int N = in_sizes[0] / 128;
    const int E = in_sizes[1] / 2;
    const int P = in_sizes[2] / 2;
    const int* esrc_in = eidx;
    const int* edst_in = eidx + E;

    // workspace layout (4-byte units)
    float* ws      = (float*)d_ws;
    int*   deg     = (int*)d_ws;                  // [N]
    float* dinv    = ws + 65536;                  // [N]
    int*   base    = (int*)(ws + 131072);         // [N+1]
    int*   bsum    = (int*)(ws + 196608);         // [256]
    f16*   Wt_gcn  = (f16*)(ws + 197120);         // [128*128] f16
    f16*   W1t     = (f16*)(ws + 205312);         // [128*256] f16
    int*   rank    = (int*)(ws + 221696);         // [E]
    int*   ecsr    = (int*)(ws + 221696 + (size_t)E);  // [E]
    __half2* Hpk   = (__half2*)(ws + 221696 + 2 * (size_t)E);  // [N*64]
    __half2* Upk   = Hpk + (size_t)N * 64;        // [N*64]
    __half2* Vpk   = Upk + (size_t)N * 64;        // [N*64]

    float* out_logit = (float*)d_out;             // [P]
    float* out_pairs = out_logit + P;             // [2P] as float
    float* out_h     = out_logit + 3 * (size_t)P; // [N*128]

    const int nb = (N + WG - 1) / WG;  // 196 <= 256
    int nI = N, eI = E, nbI = nb, p4 = P / 2;
    void* csr_args[] = {
        (void*)&esrc_in, (void*)&edst_in, (void*)&deg, (void*)&rank, (void*)&base,
        (void*)&bsum, (void*)&dinv, (void*)&W_gcn, (void*)&Wt_gcn, (void*)&W1,
        (void*)&W1t, (void*)&pairs, (void*)&out_pairs, (void*)&ecsr,
        (void*)&nI, (void*)&eI, (void*)&nbI, (void*)&p4};
    hipLaunchCooperativeKernel((const void*)k_csr, dim3(1024), dim3(WG), csr_args, 0, stream);

    dim3 blk(WG);
    dim3 grid_pair((unsigned)((P + 31) / 32));
    k_mm_hpk   <<<(N + 63) / 64, blk, 0, stream>>>(x, Wt_gcn, dinv, Hpk, N);
    k_gather_uv<<<(N + 63) / 64, blk, 0, stream>>>(Hpk, dinv, b_gcn, base, ecsr, W1t, b1,
                                                   out_h, Upk, Vpk, N);
    k_pair8    <<<grid_pair, blk, 0, stream>>>(Upk, Vpk, W2, b2, pairs, out_logit, P);
}